// Round 4
// baseline (420.593 us; speedup 1.0000x reference)
//
#include <hip/hip_runtime.h>
#include <hip/hip_bf16.h>
#include <math.h>

#define BB 16
#define SS 4096
#define IN 64
#define DD 256
#define NN 16
#define KK 32
#define CH 32
#define LCH 128
#define BS (BB*SS)

typedef __attribute__((ext_vector_type(4))) float f32x4;
typedef __attribute__((ext_vector_type(8))) short bf16x8;

__device__ __forceinline__ float bf2f(unsigned short u){
  return __uint_as_float(((unsigned int)u)<<16);
}
__device__ __forceinline__ unsigned short f2bf(float f){
  unsigned int u = __float_as_uint(f);
  return (unsigned short)((u + 0x7fffu + ((u>>16)&1u)) >> 16);
}
// XOR-swizzled LDS addressing for 64x(256 bf16) tiles: row stride 512B,
// 16B slot index XORed with (row&7) -> conflict-free ds_read_b128 down columns.
__device__ __forceinline__ void* swz(void* base, int row, int byteoff){
  return (void*)((char*)base + (row<<9) + (byteoff ^ ((row&7)<<4)));
}
// FFT LDS swizzle on float2 index: involution, scrambles low4 with bits[7:4].
#define SW(i) ((i) ^ (((i)>>4)&15))

// ---------------- prep: transpose+bf16 weights, bias concat, twiddles ----------------
__global__ void k_prep(const float* Wd, const float* Wg, const float* WB, const float* WC,
                       const float* bBv, const float* bCv,
                       unsigned short* WdT, unsigned short* WgT, unsigned short* WbcT,
                       float* bbc, float2* tw){
  int id = blockIdx.x*256 + threadIdx.x;
  if (id < 65536){ int n = id>>8, k = id&255; WdT[id] = f2bf(Wd[k*256+n]); }
  else if (id < 131072){ int j = id-65536; int n=j>>8, k=j&255; WgT[j] = f2bf(Wg[k*256+n]); }
  else if (id < 139264){ int j = id-131072; int n=j>>8, k=j&255;
    WbcT[j] = f2bf(n<16 ? WB[k*16+n] : WC[k*16+(n-16)]); }
  else if (id < 141312){ int k = id-139264;
    double a = -6.283185307179586476925287 * (double)k / 4096.0;
    tw[k] = make_float2((float)cos(a), (float)sin(a)); }
  else if (id < 141344){ int j = id-141312; bbc[j] = (j<16)? bBv[j] : bCv[j-16]; }
}

// ---------------- K1: xp = x @ W_in + b_in (f32) ----------------
__global__ __launch_bounds__(256) void k_xp(const float* x, const float* W_in, const float* b_in, float* xp){
  __shared__ float xl[16][68];
  int tid = threadIdx.x;
  int m0 = blockIdx.x*16;
  {
    int r = tid>>4, kq = tid&15;
    float4 v = *(const float4*)&x[(size_t)(m0+r)*IN + kq*4];
    *(float4*)&xl[r][kq*4] = v;
  }
  __syncthreads();
  int ty = tid>>6, tx = tid&63;
  int c0 = tx*4;
  float acc[4][4] = {};
  #pragma unroll 8
  for (int k=0;k<IN;k++){
    float4 wv = *(const float4*)&W_in[k*DD + c0];
    #pragma unroll
    for (int rr=0;rr<4;rr++){
      float xv = xl[ty*4+rr][k];
      acc[rr][0] = fmaf(xv, wv.x, acc[rr][0]);
      acc[rr][1] = fmaf(xv, wv.y, acc[rr][1]);
      acc[rr][2] = fmaf(xv, wv.z, acc[rr][2]);
      acc[rr][3] = fmaf(xv, wv.w, acc[rr][3]);
    }
  }
  float4 bv = *(const float4*)&b_in[c0];
  #pragma unroll
  for (int rr=0;rr<4;rr++){
    float4 o = make_float4(acc[rr][0]+bv.x, acc[rr][1]+bv.y, acc[rr][2]+bv.z, acc[rr][3]+bv.w);
    *(float4*)&xp[(size_t)(m0+ty*4+rr)*DD + c0] = o;
  }
}

// ---------------- K2: LayerNorm + depthwise conv(3) + silu ----------------
__global__ __launch_bounds__(256) void k_lnconv(const float* xp, const float* ln1_g, const float* ln1_b,
      const float* conv_w, const float* conv_b,
      unsigned short* xn16, unsigned short* u16){
  __shared__ float xs[18][260];
  __shared__ float lg[DD], lb[DD], c0w[DD], c1w[DD], c2w[DD], cbv[DD];
  int tid = threadIdx.x;
  int b = blockIdx.y; int t0 = blockIdx.x*16;
  lg[tid]=ln1_g[tid]; lb[tid]=ln1_b[tid];
  c0w[tid]=conv_w[tid*3]; c1w[tid]=conv_w[tid*3+1]; c2w[tid]=conv_w[tid*3+2];
  cbv[tid]=conv_b[tid];
  __syncthreads();
  int w = tid>>6, lane = tid&63;
  for (int r=w; r<18; r+=4){
    int t = t0 - 1 + r;
    bool valid = (t>=0) && (t<SS);
    float4 v = make_float4(0.f,0.f,0.f,0.f);
    if (valid) v = *(const float4*)&xp[((size_t)b*SS + t)*DD + lane*4];
    float s1 = v.x+v.y+v.z+v.w;
    float s2 = v.x*v.x+v.y*v.y+v.z*v.z+v.w*v.w;
    #pragma unroll
    for (int off=32; off; off>>=1){ s1 += __shfl_xor(s1,off); s2 += __shfl_xor(s2,off); }
    float mean = s1*(1.f/256.f);
    float var  = s2*(1.f/256.f) - mean*mean;
    float rstd = rsqrtf(var + 1e-5f);
    float vv[4] = {v.x,v.y,v.z,v.w};
    float o[4];
    #pragma unroll
    for (int i=0;i<4;i++){
      int d = lane*4+i;
      o[i] = valid ? ((vv[i]-mean)*rstd*lg[d] + lb[d]) : 0.f;
      xs[r][d] = o[i];
    }
    if (r>=1 && r<=16){
      ushort4 st;
      st.x=f2bf(o[0]); st.y=f2bf(o[1]); st.z=f2bf(o[2]); st.w=f2bf(o[3]);
      *(ushort4*)&xn16[((size_t)b*SS + t)*DD + lane*4] = st;
    }
  }
  __syncthreads();
  int d = tid;
  float w0=c0w[d], w1=c1w[d], w2=c2w[d], cb=cbv[d];
  #pragma unroll 4
  for (int rr=0; rr<16; rr++){
    float a0=xs[rr][d], a1=xs[rr+1][d], a2=xs[rr+2][d];
    float xc = a0*w0 + a1*w1 + a2*w2 + cb;
    float uu = xc / (1.f + expf(-xc));
    u16[((size_t)b*SS + (t0+rr))*DD + d] = f2bf(uu);
  }
}

// ---------------- transpose xp -> paired-complex xpz [B][D/2][S] (float2 = d-pair) ----------------
__global__ void k_transpose(const float* xp, float2* xpz){
  __shared__ float tile[32][33];
  int b = blockIdx.z; int s0 = blockIdx.x*32; int d0 = blockIdx.y*32;
  int tx = threadIdx.x, ty = threadIdx.y;
  const float* src = xp + (size_t)b*SS*DD;
  #pragma unroll
  for (int i=0;i<4;i++) tile[ty+8*i][tx] = src[(size_t)(s0+ty+8*i)*DD + d0+tx];
  __syncthreads();
  float2* dst = xpz + (size_t)b*128*SS;
  #pragma unroll
  for (int i=0;i<2;i++){
    int pr = ty + 8*i;                 // local pair 0..15
    dst[(size_t)((d0>>1) + pr)*SS + s0 + tx] =
        make_float2(tile[tx][2*pr], tile[tx][2*pr+1]);
  }
}

// ---------------- fused single-pass GEMM: 64 rows x all-N, A in LDS, B from L2 ----------------
// NTOT = number of 16-col fragments total (18 = Wd(16)+WB/WC(2) fused; 16 = Wg).
// ACT applies to frags jn<16: 1=softplus, 2=silu. Frags jn>=16 (bc) get no act.
template<int NTOT, int ACT>
__global__ __launch_bounds__(512,4) void k_gemm2(const unsigned short* Ab, const unsigned short* Bt,
      const float* bias_main, const float* bias_bc,
      unsigned short* out_main, unsigned short* out_bc){
  __shared__ unsigned short As[64*256];   // 32 KiB
  const int NF = NTOT/2;
  int tid = threadIdx.x;
  int m0 = blockIdx.x*64;
  {
    const uint4* gA = (const uint4*)(Ab + (size_t)m0*256);
    #pragma unroll
    for (int i=0;i<4;i++){
      int f = tid + 512*i;               // f < 2048; row = f>>5 < 64
      uint4 v = gA[f];
      *(uint4*)swz(As, f>>5, (f&31)<<4) = v;
    }
  }
  __syncthreads();
  int wv = tid>>6, lane = tid&63;
  int wm = wv>>1, nh = wv&1;            // 4 m-waves x 2 n-halves
  int lr = lane&15, lh = lane>>4;
  f32x4 acc[NF];
  #pragma unroll
  for (int j=0;j<NF;j++){ acc[j][0]=0.f; acc[j][1]=0.f; acc[j][2]=0.f; acc[j][3]=0.f; }
  #pragma unroll
  for (int kc=0;kc<8;kc++){
    bf16x8 af = *(const bf16x8*)swz(As, wm*16+lr, kc*64+lh*16);
    #pragma unroll
    for (int j=0;j<NF;j++){
      int jn = nh*NF + j;
      bf16x8 bfv = *(const bf16x8*)&Bt[(size_t)(jn*16+lr)*256 + kc*32 + lh*8];
      acc[j] = __builtin_amdgcn_mfma_f32_16x16x32_bf16(af, bfv, acc[j], 0,0,0);
    }
  }
  #pragma unroll
  for (int j=0;j<NF;j++){
    int jn = nh*NF + j;
    if (jn < 16){
      int col = jn*16 + lr;
      float bs = bias_main[col];
      #pragma unroll
      for (int i=0;i<4;i++){
        int row = m0 + wm*16 + lh*4 + i;
        float v = acc[j][i] + bs;
        if (ACT==1) v = (v>20.f) ? v : log1pf(expf(v));
        if (ACT==2) v = v / (1.f + expf(-v));
        out_main[(size_t)row*256 + col] = f2bf(v);
      }
    } else {
      int col = (jn-16)*16 + lr;
      float bs = bias_bc[col];
      #pragma unroll
      for (int i=0;i<4;i++){
        int row = m0 + wm*16 + lh*4 + i;
        out_bc[(size_t)row*32 + col] = f2bf(acc[j][i] + bs);
      }
    }
  }
}

// ---------------- FFT: two-for-one 4096-pt radix-4 Stockham; DC rank + T0 for 2 channels ----------------
__global__ __launch_bounds__(256,2) void k_fft(const float2* xpz, const float2* twg, int* rank, float* T0){
  __shared__ float2 bufA[4096];
  __shared__ float2 bufB[4096];
  int blk = blockIdx.x;              // 0..2047
  int b = blk >> 7, pair = blk & 127;
  int tid = threadIdx.x;
  const float4* src4 = (const float4*)(xpz + ((size_t)b*128 + pair)*SS);
  #pragma unroll
  for (int q=tid; q<2048; q+=256){
    float4 v = src4[q];
    bufA[SW(2*q)]   = make_float2(v.x, v.y);
    bufA[SW(2*q+1)] = make_float2(v.z, v.w);
  }
  __syncthreads();
  float2* s = bufA; float2* d = bufB;
  for (int st=0; st<6; st++){
    int m = 1<<(2*st);
    #pragma unroll
    for (int it=0; it<4; it++){
      int i = tid + 256*it;          // i in [0,1024)
      int k4 = i & (m-1);
      int tb = i - k4;               // j4*m < 1024
      float2 a0 = s[SW(i)];
      float2 a1 = s[SW(i+1024)];
      float2 a2 = s[SW(i+2048)];
      float2 a3 = s[SW(i+3072)];
      float2 w1 = twg[tb];
      float2 w2 = make_float2(fmaf(w1.x,w1.x,-w1.y*w1.y), 2.f*w1.x*w1.y);
      float2 w3 = make_float2(fmaf(w1.x,w2.x,-w1.y*w2.y), fmaf(w1.x,w2.y, w1.y*w2.x));
      float s0x=a0.x+a2.x, s0y=a0.y+a2.y;
      float s1x=a0.x-a2.x, s1y=a0.y-a2.y;
      float s2x=a1.x+a3.x, s2y=a1.y+a3.y;
      float t3x=a1.y-a3.y, t3y=a3.x-a1.x;     // -i*(a1-a3)
      int base = 4*i - 3*k4;
      d[SW(base)] = make_float2(s0x+s2x, s0y+s2y);
      float b1x = s1x+t3x, b1y = s1y+t3y;
      d[SW(base+m)]   = make_float2(fmaf(w1.x,b1x,-w1.y*b1y), fmaf(w1.x,b1y, w1.y*b1x));
      float b2x = s0x-s2x, b2y = s0y-s2y;
      d[SW(base+2*m)] = make_float2(fmaf(w2.x,b2x,-w2.y*b2y), fmaf(w2.x,b2y, w2.y*b2x));
      float b3x = s1x-t3x, b3y = s1y-t3y;
      d[SW(base+3*m)] = make_float2(fmaf(w3.x,b3x,-w3.y*b3y), fmaf(w3.x,b3y, w3.y*b3x));
    }
    __syncthreads();
    float2* t = s; s = d; d = t;
  }
  // 6 swaps -> result (natural order) back in bufA == s; bufB dead
  float2 z0 = s[0];
  float thx = 4.f*z0.x*z0.x, thy = 4.f*z0.y*z0.y;
  int cx=0, cy=0;
  #pragma unroll
  for (int j=0;j<8;j++){
    int f = 1 + tid + 256*j;         // bins 1..2048
    float2 zf = s[SW(f)];
    float2 zc = s[SW(4096-f)];
    float sxr = zf.x+zc.x, sxi = zf.y-zc.y;   // Zf + conj(Z_{N-f})
    float syr = zf.x-zc.x, syi = zf.y+zc.y;   // Zf - conj(Z_{N-f})
    cx += (fmaf(sxr,sxr,sxi*sxi) > thx) ? 1 : 0;
    cy += (fmaf(syr,syr,syi*syi) > thy) ? 1 : 0;
  }
  #pragma unroll
  for (int off=32; off; off>>=1){ cx += __shfl_xor(cx, off); cy += __shfl_xor(cy, off); }
  int* scr = (int*)bufB;
  if ((tid&63)==0){ scr[tid>>6] = cx; scr[4+(tid>>6)] = cy; }
  __syncthreads();
  if (tid==0){
    int r0 = b*256 + 2*pair;
    rank[r0]   = scr[0]+scr[1]+scr[2]+scr[3];
    rank[r0+1] = scr[4]+scr[5]+scr[6]+scr[7];
    T0[r0]   = z0.x;
    T0[r0+1] = z0.y;
  }
}

// ---------------- scan pass A: per-chunk (A,B) composition ----------------
__global__ __launch_bounds__(256) void k_scanA(const unsigned short* d16, const unsigned short* u16,
      const unsigned short* bc16, const float* Aw, float* AB_A, float* AB_B){
  __shared__ float duo[16][2*LCH+4];   // [dcol][{de,du} x t]
  __shared__ float bmL[16][LCH+4];     // [n][t]
  int c = blockIdx.x, dg = blockIdx.y, b = blockIdx.z;
  int t0 = c*LCH, d0 = dg*16;
  int tid = threadIdx.x;
  {
    int tt = tid>>1, half = tid&1;
    size_t base = ((size_t)b*SS + (t0+tt))*DD + d0 + half*8;
    uint4 dv = *(const uint4*)(d16 + base);
    uint4 uv = *(const uint4*)(u16 + base);
    const unsigned short* dp=(const unsigned short*)&dv;
    const unsigned short* up=(const unsigned short*)&uv;
    #pragma unroll
    for (int i=0;i<8;i++){
      float d_ = bf2f(dp[i]);
      duo[half*8+i][2*tt]   = d_;
      duo[half*8+i][2*tt+1] = d_*bf2f(up[i]);
    }
    size_t bbi = ((size_t)b*SS + (t0+tt))*32 + half*8;
    uint4 bv = *(const uint4*)(bc16 + bbi);
    const unsigned short* bp=(const unsigned short*)&bv;
    #pragma unroll
    for (int i=0;i<8;i++) bmL[half*8+i][tt] = bf2f(bp[i]);
  }
  __syncthreads();
  int n = tid&15, dl = tid>>4;
  float aw = Aw[(d0+dl)*16 + n];
  float Ac = 1.f, Bc = 0.f;
  #pragma unroll
  for (int tt=0; tt<LCH; tt+=4){
    float4 bm4 = *(const float4*)&bmL[n][tt];
    float4 q0  = *(const float4*)&duo[dl][2*tt];
    float4 q1  = *(const float4*)&duo[dl][2*tt+4];
    float a;
    a = fmaf(q0.x, aw, 1.f); Ac *= a; Bc = fmaf(a, Bc, q0.y*bm4.x);
    a = fmaf(q0.z, aw, 1.f); Ac *= a; Bc = fmaf(a, Bc, q0.w*bm4.y);
    a = fmaf(q1.x, aw, 1.f); Ac *= a; Bc = fmaf(a, Bc, q1.y*bm4.z);
    a = fmaf(q1.z, aw, 1.f); Ac *= a; Bc = fmaf(a, Bc, q1.w*bm4.w);
  }
  int idx = c*65536 + b*4096 + (d0+dl)*16 + n;
  AB_A[idx] = Ac;
  AB_B[idx] = Bc;
}

// ---------------- scan pass B: prefix over chunks ----------------
__global__ void k_scanB(const float* AB_A, const float* AB_B, float* Hs){
  int tid = blockIdx.x*256 + threadIdx.x;
  float h = 0.f;
  #pragma unroll
  for (int c=0;c<CH;c++){
    Hs[c*65536 + tid] = h;
    h = fmaf(AB_A[c*65536 + tid], h, AB_B[c*65536 + tid]);
  }
}

// ---------------- scan pass C: re-scan, accumulate sum_t (y*g) per (b,d,chunk) ----------------
__global__ __launch_bounds__(256) void k_scanC(const unsigned short* d16, const unsigned short* u16,
      const unsigned short* bc16, const unsigned short* g16, const float* Aw, const float* Hs, float* part){
  __shared__ float duo[16][2*LCH+4];   // [dcol][{de,du} x t]
  __shared__ float ggL[16][LCH+4];     // [dcol][t]
  __shared__ float bcp[16][2*LCH+4];   // [n][{bm,cm} x t]
  int c = blockIdx.x, dg = blockIdx.y, b = blockIdx.z;
  int t0 = c*LCH, d0 = dg*16;
  int tid = threadIdx.x;
  {
    int tt = tid>>1, half = tid&1;
    size_t base = ((size_t)b*SS + (t0+tt))*DD + d0 + half*8;
    uint4 dv = *(const uint4*)(d16 + base);
    uint4 uv = *(const uint4*)(u16 + base);
    uint4 gv = *(const uint4*)(g16 + base);
    size_t bbi = ((size_t)b*SS + (t0+tt))*32 + half*8;
    uint4 bv = *(const uint4*)(bc16 + bbi);
    uint4 cv = *(const uint4*)(bc16 + bbi + 16);
    const unsigned short* dp=(const unsigned short*)&dv;
    const unsigned short* up=(const unsigned short*)&uv;
    const unsigned short* gp=(const unsigned short*)&gv;
    const unsigned short* bp=(const unsigned short*)&bv;
    const unsigned short* cp=(const unsigned short*)&cv;
    #pragma unroll
    for (int i=0;i<8;i++){
      float d_ = bf2f(dp[i]);
      duo[half*8+i][2*tt]   = d_;
      duo[half*8+i][2*tt+1] = d_*bf2f(up[i]);
      ggL[half*8+i][tt]     = bf2f(gp[i]);
      bcp[half*8+i][2*tt]   = bf2f(bp[i]);
      bcp[half*8+i][2*tt+1] = bf2f(cp[i]);
    }
  }
  __syncthreads();
  int n = tid&15, dl = tid>>4;
  float aw = Aw[(d0+dl)*16 + n];
  float h = Hs[c*65536 + b*4096 + (d0+dl)*16 + n];
  float acc = 0.f;
  #pragma unroll
  for (int tt=0; tt<LCH; tt+=4){
    float4 gg4 = *(const float4*)&ggL[dl][tt];
    float4 q0  = *(const float4*)&duo[dl][2*tt];
    float4 q1  = *(const float4*)&duo[dl][2*tt+4];
    float4 p0  = *(const float4*)&bcp[n][2*tt];
    float4 p1  = *(const float4*)&bcp[n][2*tt+4];
    float a;
    a = fmaf(q0.x, aw, 1.f); h = fmaf(a, h, q0.y*p0.x); acc = fmaf(p0.y*gg4.x, h, acc);
    a = fmaf(q0.z, aw, 1.f); h = fmaf(a, h, q0.w*p0.z); acc = fmaf(p0.w*gg4.y, h, acc);
    a = fmaf(q1.x, aw, 1.f); h = fmaf(a, h, q1.y*p1.x); acc = fmaf(p1.y*gg4.z, h, acc);
    a = fmaf(q1.z, aw, 1.f); h = fmaf(a, h, q1.w*p1.z); acc = fmaf(p1.w*gg4.w, h, acc);
  }
  #pragma unroll
  for (int off=8; off; off>>=1) acc += __shfl_xor(acc, off, 16);
  if (n==0) part[(size_t)(b*256 + d0+dl)*CH + c] = acc;
}

// ---------------- final: zp assembly + LN + 2-layer MLP ----------------
__global__ __launch_bounds__(256) void k_final(const float* part, const float* T0, const int* rank,
      const float* alpha, const float* beta, const float* filt_re,
      const float* lnc_g, const float* lnc_b,
      const float* W1, const float* b1, const float* W2, const float* b2,
      float* out){
  __shared__ float zs[256];
  __shared__ float h1[128];
  __shared__ float red[8];
  int b = blockIdx.x, d = threadIdx.x;
  int row = b*256 + d;
  float ps = 0.f;
  #pragma unroll
  for (int c=0;c<CH;c++) ps += part[(size_t)row*CH + c];
  float ssm_mean = ps * (1.f/4096.f);
  float t0v = T0[row];
  float mxp = t0v * (1.f/4096.f);
  int r = rank[row];
  float spec = (r < KK) ? t0v * filt_re[r*DD + d] * (1.f/4096.f) : 0.f;
  float zp = alpha[d]*(mxp + ssm_mean) + beta[d]*spec;
  float s1 = zp, s2 = zp*zp;
  #pragma unroll
  for (int off=32; off; off>>=1){ s1 += __shfl_xor(s1,off); s2 += __shfl_xor(s2,off); }
  if ((d&63)==0){ red[d>>6] = s1; red[4+(d>>6)] = s2; }
  __syncthreads();
  float mean = (red[0]+red[1]+red[2]+red[3]) * (1.f/256.f);
  float var  = (red[4]+red[5]+red[6]+red[7]) * (1.f/256.f) - mean*mean;
  float ln = (zp-mean)*rsqrtf(var+1e-5f)*lnc_g[d] + lnc_b[d];
  zs[d] = ln;
  __syncthreads();
  if (d < 128){
    float acc = b1[d];
    #pragma unroll 16
    for (int k=0;k<256;k++) acc = fmaf(zs[k], W1[k*128+d], acc);
    h1[d] = fmaxf(acc, 0.f);
  }
  __syncthreads();
  if (d < 2){
    float acc = b2[d];
    #pragma unroll 16
    for (int k=0;k<128;k++) acc = fmaf(h1[k], W2[k*2+d], acc);
    out[b*2+d] = acc;
  }
}

extern "C" void kernel_launch(void* const* d_in, const int* in_sizes, int n_in,
                              void* d_out, int out_size, void* d_ws, size_t ws_size,
                              hipStream_t stream){
  const float* x      = (const float*)d_in[0];
  const float* W_in   = (const float*)d_in[1];
  const float* b_in   = (const float*)d_in[2];
  const float* ln1_g  = (const float*)d_in[3];
  const float* ln1_b  = (const float*)d_in[4];
  const float* conv_w = (const float*)d_in[5];
  const float* conv_b = (const float*)d_in[6];
  const float* Wd     = (const float*)d_in[7];
  const float* bd     = (const float*)d_in[8];
  const float* WB     = (const float*)d_in[9];
  const float* bB     = (const float*)d_in[10];
  const float* WC     = (const float*)d_in[11];
  const float* bC     = (const float*)d_in[12];
  const float* A      = (const float*)d_in[13];
  const float* Wg     = (const float*)d_in[14];
  const float* bg     = (const float*)d_in[15];
  const float* filt_re= (const float*)d_in[16];
  const float* alpha  = (const float*)d_in[18];
  const float* beta   = (const float*)d_in[19];
  const float* lnc_g  = (const float*)d_in[20];
  const float* lnc_b  = (const float*)d_in[21];
  const float* W1     = (const float*)d_in[22];
  const float* b1     = (const float*)d_in[23];
  const float* W2     = (const float*)d_in[24];
  const float* b2     = (const float*)d_in[25];

  char* w = (char*)d_ws;
  float* xp   = (float*)(w);
  unsigned short* d16  = (unsigned short*)(w);
  unsigned short* bc16 = (unsigned short*)(w + 33554432);
  float2* xpz = (float2*)(w + 67108864);
  float* AB_A = (float*)(w + 67108864);
  float* AB_B = (float*)(w + 67108864 + 8388608);
  float* Hs   = (float*)(w + 67108864 + 16777216);
  float* part = (float*)(w + 67108864 + 25165824);
  unsigned short* xn16 = (unsigned short*)(w + 134217728);
  unsigned short* u16  = (unsigned short*)(w + 167772160);
  unsigned short* g16  = (unsigned short*)(w + 201326592);
  char* small = w + 234881024;
  // WdT (131072B) immediately followed by WbcT (16384B): fused 288x256 B matrix.
  unsigned short* WdT  = (unsigned short*)(small);
  unsigned short* WbcT = (unsigned short*)(small + 131072);
  unsigned short* WgT  = (unsigned short*)(small + 147456);
  float*  bbc = (float*)(small + 278528);
  float2* tw  = (float2*)(small + 278656);
  float*  T0  = (float*)(small + 295040);
  int*    rank= (int*)(small + 311424);
  (void)in_sizes; (void)n_in; (void)out_size; (void)ws_size;

  hipLaunchKernelGGL(k_prep, dim3(553), dim3(256), 0, stream,
                     Wd, Wg, WB, WC, bB, bC, WdT, WgT, WbcT, bbc, tw);
  hipLaunchKernelGGL(k_xp, dim3(BS/16), dim3(256), 0, stream, x, W_in, b_in, xp);
  hipLaunchKernelGGL(k_lnconv, dim3(SS/16, BB), dim3(256), 0, stream,
                     xp, ln1_g, ln1_b, conv_w, conv_b, xn16, u16);
  hipLaunchKernelGGL(k_transpose, dim3(SS/32, DD/32, BB), dim3(32,8), 0, stream, xp, xpz);
  hipLaunchKernelGGL(k_fft, dim3(BB*128), dim3(256), 0, stream, xpz, tw, rank, T0);
  hipLaunchKernelGGL((k_gemm2<18,1>), dim3(BS/64), dim3(512), 0, stream,
                     u16, WdT, bd, bbc, d16, bc16);
  hipLaunchKernelGGL((k_gemm2<16,2>), dim3(BS/64), dim3(512), 0, stream,
                     xn16, WgT, bg, bbc, g16, bc16);
  hipLaunchKernelGGL(k_scanA, dim3(CH, DD/16, BB), dim3(256), 0, stream, d16, u16, bc16, A, AB_A, AB_B);
  hipLaunchKernelGGL(k_scanB, dim3(256), dim3(256), 0, stream, AB_A, AB_B, Hs);
  hipLaunchKernelGGL(k_scanC, dim3(CH, DD/16, BB), dim3(256), 0, stream, d16, u16, bc16, g16, A, Hs, part);
  hipLaunchKernelGGL(k_final, dim3(BB), dim3(256), 0, stream,
                     part, T0, rank, alpha, beta, filt_re, lnc_g, lnc_b, W1, b1, W2, b2, (float*)d_out);
}

// Round 5
// 344.882 us; speedup vs baseline: 1.2195x; 1.2195x over previous
//
#include <hip/hip_runtime.h>
#include <hip/hip_bf16.h>
#include <math.h>

#define BB 16
#define SS 4096
#define IN 64
#define DD 256
#define NN 16
#define KK 32
#define CH 32
#define LCH 128
#define BS (BB*SS)

typedef __attribute__((ext_vector_type(4))) float f32x4;
typedef __attribute__((ext_vector_type(8))) short bf16x8;

__device__ __forceinline__ float bf2f(unsigned short u){
  return __uint_as_float(((unsigned int)u)<<16);
}
__device__ __forceinline__ unsigned short f2bf(float f){
  unsigned int u = __float_as_uint(f);
  return (unsigned short)((u + 0x7fffu + ((u>>16)&1u)) >> 16);
}
// XOR-swizzled LDS addressing for 64x(256 bf16) tiles: row stride 512B,
// 16B slot index XORed with (row&7) -> conflict-free ds_read_b128 down columns.
__device__ __forceinline__ void* swz(void* base, int row, int byteoff){
  return (void*)((char*)base + (row<<9) + (byteoff ^ ((row&7)<<4)));
}
// FFT LDS swizzle on float2 index: involution, scrambles low4 with bits[7:4].
#define SW(i) ((i) ^ (((i)>>4)&15))

// ---------------- prep: fragment-major bf16 weights, bias concat, twiddles ----------------
// Frag-major layout: element for (jn, kc, lane, e) at ((jn*8+kc)*64+lane)*8+e,
// where lr=lane&15, lh=lane>>4, col n=jn*16+lr, row k=kc*32+lh*8+e.
// -> each MFMA B-fragment load is one lane-contiguous 1 KiB transaction.
__global__ void k_prep(const float* Wd, const float* Wg, const float* WB, const float* WC,
                       const float* bBv, const float* bCv,
                       unsigned short* WdF, unsigned short* WgF,
                       float* bbc, float2* tw){
  int id = blockIdx.x*256 + threadIdx.x;
  if (id < 73728){                     // fused Wd(jn 0..15) + WB/WC(jn 16,17)
    int jn = id >> 12; int rem = id & 4095;
    int kc = rem >> 9; int l8 = (rem >> 3) & 63; int e = id & 7;
    int lr = l8 & 15, lh = l8 >> 4;
    int k = kc*32 + lh*8 + e;
    float v;
    if (jn < 16){ int n = jn*16 + lr; v = Wd[k*256+n]; }
    else { int c = (jn-16)*16 + lr; v = (c<16) ? WB[k*16+c] : WC[k*16+(c-16)]; }
    WdF[id] = f2bf(v);
  }
  else if (id < 139264){               // Wg frag-major (jn 0..15)
    int o = id - 73728;
    int jn = o >> 12; int rem = o & 4095;
    int kc = rem >> 9; int l8 = (rem >> 3) & 63; int e = o & 7;
    int lr = l8 & 15, lh = l8 >> 4;
    int k = kc*32 + lh*8 + e;
    WgF[o] = f2bf(Wg[k*256 + jn*16 + lr]);
  }
  else if (id < 141312){ int k = id-139264;
    double a = -6.283185307179586476925287 * (double)k / 4096.0;
    tw[k] = make_float2((float)cos(a), (float)sin(a)); }
  else if (id < 141344){ int j = id-141312; bbc[j] = (j<16)? bBv[j] : bCv[j-16]; }
}

// ---------------- K1: xp = x @ W_in + b_in (f32) ----------------
__global__ __launch_bounds__(256) void k_xp(const float* x, const float* W_in, const float* b_in, float* xp){
  __shared__ float xl[16][68];
  int tid = threadIdx.x;
  int m0 = blockIdx.x*16;
  {
    int r = tid>>4, kq = tid&15;
    float4 v = *(const float4*)&x[(size_t)(m0+r)*IN + kq*4];
    *(float4*)&xl[r][kq*4] = v;
  }
  __syncthreads();
  int ty = tid>>6, tx = tid&63;
  int c0 = tx*4;
  float acc[4][4] = {};
  #pragma unroll 8
  for (int k=0;k<IN;k++){
    float4 wv = *(const float4*)&W_in[k*DD + c0];
    #pragma unroll
    for (int rr=0;rr<4;rr++){
      float xv = xl[ty*4+rr][k];
      acc[rr][0] = fmaf(xv, wv.x, acc[rr][0]);
      acc[rr][1] = fmaf(xv, wv.y, acc[rr][1]);
      acc[rr][2] = fmaf(xv, wv.z, acc[rr][2]);
      acc[rr][3] = fmaf(xv, wv.w, acc[rr][3]);
    }
  }
  float4 bv = *(const float4*)&b_in[c0];
  #pragma unroll
  for (int rr=0;rr<4;rr++){
    float4 o = make_float4(acc[rr][0]+bv.x, acc[rr][1]+bv.y, acc[rr][2]+bv.z, acc[rr][3]+bv.w);
    *(float4*)&xp[(size_t)(m0+ty*4+rr)*DD + c0] = o;
  }
}

// ---------------- K2: LayerNorm + depthwise conv(3) + silu ----------------
__global__ __launch_bounds__(256) void k_lnconv(const float* xp, const float* ln1_g, const float* ln1_b,
      const float* conv_w, const float* conv_b,
      unsigned short* xn16, unsigned short* u16){
  __shared__ float xs[18][260];
  __shared__ float lg[DD], lb[DD], c0w[DD], c1w[DD], c2w[DD], cbv[DD];
  int tid = threadIdx.x;
  int b = blockIdx.y; int t0 = blockIdx.x*16;
  lg[tid]=ln1_g[tid]; lb[tid]=ln1_b[tid];
  c0w[tid]=conv_w[tid*3]; c1w[tid]=conv_w[tid*3+1]; c2w[tid]=conv_w[tid*3+2];
  cbv[tid]=conv_b[tid];
  __syncthreads();
  int w = tid>>6, lane = tid&63;
  for (int r=w; r<18; r+=4){
    int t = t0 - 1 + r;
    bool valid = (t>=0) && (t<SS);
    float4 v = make_float4(0.f,0.f,0.f,0.f);
    if (valid) v = *(const float4*)&xp[((size_t)b*SS + t)*DD + lane*4];
    float s1 = v.x+v.y+v.z+v.w;
    float s2 = v.x*v.x+v.y*v.y+v.z*v.z+v.w*v.w;
    #pragma unroll
    for (int off=32; off; off>>=1){ s1 += __shfl_xor(s1,off); s2 += __shfl_xor(s2,off); }
    float mean = s1*(1.f/256.f);
    float var  = s2*(1.f/256.f) - mean*mean;
    float rstd = rsqrtf(var + 1e-5f);
    float vv[4] = {v.x,v.y,v.z,v.w};
    float o[4];
    #pragma unroll
    for (int i=0;i<4;i++){
      int d = lane*4+i;
      o[i] = valid ? ((vv[i]-mean)*rstd*lg[d] + lb[d]) : 0.f;
      xs[r][d] = o[i];
    }
    if (r>=1 && r<=16){
      ushort4 st;
      st.x=f2bf(o[0]); st.y=f2bf(o[1]); st.z=f2bf(o[2]); st.w=f2bf(o[3]);
      *(ushort4*)&xn16[((size_t)b*SS + t)*DD + lane*4] = st;
    }
  }
  __syncthreads();
  int d = tid;
  float w0=c0w[d], w1=c1w[d], w2=c2w[d], cb=cbv[d];
  #pragma unroll 4
  for (int rr=0; rr<16; rr++){
    float a0=xs[rr][d], a1=xs[rr+1][d], a2=xs[rr+2][d];
    float xc = a0*w0 + a1*w1 + a2*w2 + cb;
    float uu = xc / (1.f + expf(-xc));
    u16[((size_t)b*SS + (t0+rr))*DD + d] = f2bf(uu);
  }
}

// ---------------- transpose xp -> paired-complex xpz [B][D/2][S] (float2 = d-pair) ----------------
__global__ void k_transpose(const float* xp, float2* xpz){
  __shared__ float tile[32][33];
  int b = blockIdx.z; int s0 = blockIdx.x*32; int d0 = blockIdx.y*32;
  int tx = threadIdx.x, ty = threadIdx.y;
  const float* src = xp + (size_t)b*SS*DD;
  #pragma unroll
  for (int i=0;i<4;i++) tile[ty+8*i][tx] = src[(size_t)(s0+ty+8*i)*DD + d0+tx];
  __syncthreads();
  float2* dst = xpz + (size_t)b*128*SS;
  #pragma unroll
  for (int i=0;i<2;i++){
    int pr = ty + 8*i;                 // local pair 0..15
    dst[(size_t)((d0>>1) + pr)*SS + s0 + tx] =
        make_float2(tile[tx][2*pr], tile[tx][2*pr+1]);
  }
}

// ---------------- fused single-pass GEMM: 64 rows x all-N, A in LDS, frag-major B from L2 ----------------
// NTOT = 16-col fragments total (18 = Wd(16)+WB/WC(2) fused; 16 = Wg).
// ACT applies to frags jn<16: 1=softplus, 2=silu. Frags jn>=16 (bc) get no act.
template<int NTOT, int ACT>
__global__ __launch_bounds__(512,2) void k_gemm2(const unsigned short* Ab, const unsigned short* Bt,
      const float* bias_main, const float* bias_bc,
      unsigned short* out_main, unsigned short* out_bc){
  __shared__ unsigned short As[64*256];   // 32 KiB
  const int NF = NTOT/2;
  int tid = threadIdx.x;
  int m0 = blockIdx.x*64;
  {
    const uint4* gA = (const uint4*)(Ab + (size_t)m0*256);
    #pragma unroll
    for (int i=0;i<4;i++){
      int f = tid + 512*i;               // f < 2048; row = f>>5 < 64
      uint4 v = gA[f];
      *(uint4*)swz(As, f>>5, (f&31)<<4) = v;
    }
  }
  __syncthreads();
  int wv = tid>>6, lane = tid&63;
  int wm = wv>>1, nh = wv&1;            // 4 m-waves x 2 n-halves
  int lr = lane&15, lh = lane>>4;
  // Hoist all 8 A-fragments into registers (done once).
  bf16x8 afr[8];
  #pragma unroll
  for (int kc=0;kc<8;kc++)
    afr[kc] = *(const bf16x8*)swz(As, wm*16+lr, kc*64+lh*16);
  f32x4 acc[NF];
  #pragma unroll
  for (int j=0;j<NF;j++){ acc[j][0]=0.f; acc[j][1]=0.f; acc[j][2]=0.f; acc[j][3]=0.f; }
  #pragma unroll
  for (int j=0;j<NF;j++){
    int jn = nh*NF + j;
    const bf16x8* bp = (const bf16x8*)(Bt + (size_t)jn*4096 + (size_t)lane*8);
    bf16x8 bq[8];
    #pragma unroll
    for (int kc=0;kc<8;kc++) bq[kc] = bp[kc*64];   // 8 coalesced 1 KiB loads, independent
    #pragma unroll
    for (int kc=0;kc<8;kc++)
      acc[j] = __builtin_amdgcn_mfma_f32_16x16x32_bf16(afr[kc], bq[kc], acc[j], 0,0,0);
  }
  #pragma unroll
  for (int j=0;j<NF;j++){
    int jn = nh*NF + j;
    if (jn < 16){
      int col = jn*16 + lr;
      float bs = bias_main[col];
      #pragma unroll
      for (int i=0;i<4;i++){
        int row = m0 + wm*16 + lh*4 + i;
        float v = acc[j][i] + bs;
        if (ACT==1) v = (v>20.f) ? v : log1pf(expf(v));
        if (ACT==2) v = v / (1.f + expf(-v));
        out_main[(size_t)row*256 + col] = f2bf(v);
      }
    } else {
      int col = (jn-16)*16 + lr;
      float bs = bias_bc[col];
      #pragma unroll
      for (int i=0;i<4;i++){
        int row = m0 + wm*16 + lh*4 + i;
        out_bc[(size_t)row*32 + col] = f2bf(acc[j][i] + bs);
      }
    }
  }
}

// ---------------- FFT: two-for-one 4096-pt radix-4 Stockham; DC rank + T0 for 2 channels ----------------
__global__ __launch_bounds__(256,2) void k_fft(const float2* xpz, const float2* twg, int* rank, float* T0){
  __shared__ float2 bufA[4096];
  __shared__ float2 bufB[4096];
  int blk = blockIdx.x;              // 0..2047
  int b = blk >> 7, pair = blk & 127;
  int tid = threadIdx.x;
  const float4* src4 = (const float4*)(xpz + ((size_t)b*128 + pair)*SS);
  #pragma unroll
  for (int q=tid; q<2048; q+=256){
    float4 v = src4[q];
    bufA[SW(2*q)]   = make_float2(v.x, v.y);
    bufA[SW(2*q+1)] = make_float2(v.z, v.w);
  }
  __syncthreads();
  float2* s = bufA; float2* d = bufB;
  for (int st=0; st<6; st++){
    int m = 1<<(2*st);
    #pragma unroll
    for (int it=0; it<4; it++){
      int i = tid + 256*it;          // i in [0,1024)
      int k4 = i & (m-1);
      int tb = i - k4;               // j4*m < 1024
      float2 a0 = s[SW(i)];
      float2 a1 = s[SW(i+1024)];
      float2 a2 = s[SW(i+2048)];
      float2 a3 = s[SW(i+3072)];
      float2 w1 = twg[tb];
      float2 w2 = make_float2(fmaf(w1.x,w1.x,-w1.y*w1.y), 2.f*w1.x*w1.y);
      float2 w3 = make_float2(fmaf(w1.x,w2.x,-w1.y*w2.y), fmaf(w1.x,w2.y, w1.y*w2.x));
      float s0x=a0.x+a2.x, s0y=a0.y+a2.y;
      float s1x=a0.x-a2.x, s1y=a0.y-a2.y;
      float s2x=a1.x+a3.x, s2y=a1.y+a3.y;
      float t3x=a1.y-a3.y, t3y=a3.x-a1.x;     // -i*(a1-a3)
      int base = 4*i - 3*k4;
      d[SW(base)] = make_float2(s0x+s2x, s0y+s2y);
      float b1x = s1x+t3x, b1y = s1y+t3y;
      d[SW(base+m)]   = make_float2(fmaf(w1.x,b1x,-w1.y*b1y), fmaf(w1.x,b1y, w1.y*b1x));
      float b2x = s0x-s2x, b2y = s0y-s2y;
      d[SW(base+2*m)] = make_float2(fmaf(w2.x,b2x,-w2.y*b2y), fmaf(w2.x,b2y, w2.y*b2x));
      float b3x = s1x-t3x, b3y = s1y-t3y;
      d[SW(base+3*m)] = make_float2(fmaf(w3.x,b3x,-w3.y*b3y), fmaf(w3.x,b3y, w3.y*b3x));
    }
    __syncthreads();
    float2* t = s; s = d; d = t;
  }
  // 6 swaps -> result (natural order) back in bufA == s; bufB dead
  float2 z0 = s[0];
  float thx = 4.f*z0.x*z0.x, thy = 4.f*z0.y*z0.y;
  int cx=0, cy=0;
  #pragma unroll
  for (int j=0;j<8;j++){
    int f = 1 + tid + 256*j;         // bins 1..2048
    float2 zf = s[SW(f)];
    float2 zc = s[SW(4096-f)];
    float sxr = zf.x+zc.x, sxi = zf.y-zc.y;   // Zf + conj(Z_{N-f})
    float syr = zf.x-zc.x, syi = zf.y+zc.y;   // Zf - conj(Z_{N-f})
    cx += (fmaf(sxr,sxr,sxi*sxi) > thx) ? 1 : 0;
    cy += (fmaf(syr,syr,syi*syi) > thy) ? 1 : 0;
  }
  #pragma unroll
  for (int off=32; off; off>>=1){ cx += __shfl_xor(cx, off); cy += __shfl_xor(cy, off); }
  int* scr = (int*)bufB;
  if ((tid&63)==0){ scr[tid>>6] = cx; scr[4+(tid>>6)] = cy; }
  __syncthreads();
  if (tid==0){
    int r0 = b*256 + 2*pair;
    rank[r0]   = scr[0]+scr[1]+scr[2]+scr[3];
    rank[r0+1] = scr[4]+scr[5]+scr[6]+scr[7];
    T0[r0]   = z0.x;
    T0[r0+1] = z0.y;
  }
}

// ---------------- scan pass A: per-chunk (A,B) composition ----------------
__global__ __launch_bounds__(256) void k_scanA(const unsigned short* d16, const unsigned short* u16,
      const unsigned short* bc16, const float* Aw, float* AB_A, float* AB_B){
  __shared__ float duo[16][2*LCH+4];   // [dcol][{de,du} x t]
  __shared__ float bmL[16][LCH+4];     // [n][t]
  int c = blockIdx.x, dg = blockIdx.y, b = blockIdx.z;
  int t0 = c*LCH, d0 = dg*16;
  int tid = threadIdx.x;
  {
    int tt = tid>>1, half = tid&1;
    size_t base = ((size_t)b*SS + (t0+tt))*DD + d0 + half*8;
    uint4 dv = *(const uint4*)(d16 + base);
    uint4 uv = *(const uint4*)(u16 + base);
    const unsigned short* dp=(const unsigned short*)&dv;
    const unsigned short* up=(const unsigned short*)&uv;
    #pragma unroll
    for (int i=0;i<8;i++){
      float d_ = bf2f(dp[i]);
      duo[half*8+i][2*tt]   = d_;
      duo[half*8+i][2*tt+1] = d_*bf2f(up[i]);
    }
    size_t bbi = ((size_t)b*SS + (t0+tt))*32 + half*8;
    uint4 bv = *(const uint4*)(bc16 + bbi);
    const unsigned short* bp=(const unsigned short*)&bv;
    #pragma unroll
    for (int i=0;i<8;i++) bmL[half*8+i][tt] = bf2f(bp[i]);
  }
  __syncthreads();
  int n = tid&15, dl = tid>>4;
  float aw = Aw[(d0+dl)*16 + n];
  float Ac = 1.f, Bc = 0.f;
  #pragma unroll
  for (int tt=0; tt<LCH; tt+=4){
    float4 bm4 = *(const float4*)&bmL[n][tt];
    float4 q0  = *(const float4*)&duo[dl][2*tt];
    float4 q1  = *(const float4*)&duo[dl][2*tt+4];
    float a;
    a = fmaf(q0.x, aw, 1.f); Ac *= a; Bc = fmaf(a, Bc, q0.y*bm4.x);
    a = fmaf(q0.z, aw, 1.f); Ac *= a; Bc = fmaf(a, Bc, q0.w*bm4.y);
    a = fmaf(q1.x, aw, 1.f); Ac *= a; Bc = fmaf(a, Bc, q1.y*bm4.z);
    a = fmaf(q1.z, aw, 1.f); Ac *= a; Bc = fmaf(a, Bc, q1.w*bm4.w);
  }
  int idx = c*65536 + b*4096 + (d0+dl)*16 + n;
  AB_A[idx] = Ac;
  AB_B[idx] = Bc;
}

// ---------------- scan pass B: prefix over chunks ----------------
__global__ void k_scanB(const float* AB_A, const float* AB_B, float* Hs){
  int tid = blockIdx.x*256 + threadIdx.x;
  float h = 0.f;
  #pragma unroll
  for (int c=0;c<CH;c++){
    Hs[c*65536 + tid] = h;
    h = fmaf(AB_A[c*65536 + tid], h, AB_B[c*65536 + tid]);
  }
}

// ---------------- scan pass C: re-scan, accumulate sum_t (y*g) per (b,d,chunk) ----------------
__global__ __launch_bounds__(256) void k_scanC(const unsigned short* d16, const unsigned short* u16,
      const unsigned short* bc16, const unsigned short* g16, const float* Aw, const float* Hs, float* part){
  __shared__ float duo[16][2*LCH+4];   // [dcol][{de,du} x t]
  __shared__ float ggL[16][LCH+4];     // [dcol][t]
  __shared__ float bcp[16][2*LCH+4];   // [n][{bm,cm} x t]
  int c = blockIdx.x, dg = blockIdx.y, b = blockIdx.z;
  int t0 = c*LCH, d0 = dg*16;
  int tid = threadIdx.x;
  {
    int tt = tid>>1, half = tid&1;
    size_t base = ((size_t)b*SS + (t0+tt))*DD + d0 + half*8;
    uint4 dv = *(const uint4*)(d16 + base);
    uint4 uv = *(const uint4*)(u16 + base);
    uint4 gv = *(const uint4*)(g16 + base);
    size_t bbi = ((size_t)b*SS + (t0+tt))*32 + half*8;
    uint4 bv = *(const uint4*)(bc16 + bbi);
    uint4 cv = *(const uint4*)(bc16 + bbi + 16);
    const unsigned short* dp=(const unsigned short*)&dv;
    const unsigned short* up=(const unsigned short*)&uv;
    const unsigned short* gp=(const unsigned short*)&gv;
    const unsigned short* bp=(const unsigned short*)&bv;
    const unsigned short* cp=(const unsigned short*)&cv;
    #pragma unroll
    for (int i=0;i<8;i++){
      float d_ = bf2f(dp[i]);
      duo[half*8+i][2*tt]   = d_;
      duo[half*8+i][2*tt+1] = d_*bf2f(up[i]);
      ggL[half*8+i][tt]     = bf2f(gp[i]);
      bcp[half*8+i][2*tt]   = bf2f(bp[i]);
      bcp[half*8+i][2*tt+1] = bf2f(cp[i]);
    }
  }
  __syncthreads();
  int n = tid&15, dl = tid>>4;
  float aw = Aw[(d0+dl)*16 + n];
  float h = Hs[c*65536 + b*4096 + (d0+dl)*16 + n];
  float acc = 0.f;
  #pragma unroll
  for (int tt=0; tt<LCH; tt+=4){
    float4 gg4 = *(const float4*)&ggL[dl][tt];
    float4 q0  = *(const float4*)&duo[dl][2*tt];
    float4 q1  = *(const float4*)&duo[dl][2*tt+4];
    float4 p0  = *(const float4*)&bcp[n][2*tt];
    float4 p1  = *(const float4*)&bcp[n][2*tt+4];
    float a;
    a = fmaf(q0.x, aw, 1.f); h = fmaf(a, h, q0.y*p0.x); acc = fmaf(p0.y*gg4.x, h, acc);
    a = fmaf(q0.z, aw, 1.f); h = fmaf(a, h, q0.w*p0.z); acc = fmaf(p0.w*gg4.y, h, acc);
    a = fmaf(q1.x, aw, 1.f); h = fmaf(a, h, q1.y*p1.x); acc = fmaf(p1.y*gg4.z, h, acc);
    a = fmaf(q1.z, aw, 1.f); h = fmaf(a, h, q1.w*p1.z); acc = fmaf(p1.w*gg4.w, h, acc);
  }
  #pragma unroll
  for (int off=8; off; off>>=1) acc += __shfl_xor(acc, off, 16);
  if (n==0) part[(size_t)(b*256 + d0+dl)*CH + c] = acc;
}

// ---------------- final: zp assembly + LN + 2-layer MLP ----------------
__global__ __launch_bounds__(256) void k_final(const float* part, const float* T0, const int* rank,
      const float* alpha, const float* beta, const float* filt_re,
      const float* lnc_g, const float* lnc_b,
      const float* W1, const float* b1, const float* W2, const float* b2,
      float* out){
  __shared__ float zs[256];
  __shared__ float h1[128];
  __shared__ float red[8];
  int b = blockIdx.x, d = threadIdx.x;
  int row = b*256 + d;
  float ps = 0.f;
  #pragma unroll
  for (int c=0;c<CH;c++) ps += part[(size_t)row*CH + c];
  float ssm_mean = ps * (1.f/4096.f);
  float t0v = T0[row];
  float mxp = t0v * (1.f/4096.f);
  int r = rank[row];
  float spec = (r < KK) ? t0v * filt_re[r*DD + d] * (1.f/4096.f) : 0.f;
  float zp = alpha[d]*(mxp + ssm_mean) + beta[d]*spec;
  float s1 = zp, s2 = zp*zp;
  #pragma unroll
  for (int off=32; off; off>>=1){ s1 += __shfl_xor(s1,off); s2 += __shfl_xor(s2,off); }
  if ((d&63)==0){ red[d>>6] = s1; red[4+(d>>6)] = s2; }
  __syncthreads();
  float mean = (red[0]+red[1]+red[2]+red[3]) * (1.f/256.f);
  float var  = (red[4]+red[5]+red[6]+red[7]) * (1.f/256.f) - mean*mean;
  float ln = (zp-mean)*rsqrtf(var+1e-5f)*lnc_g[d] + lnc_b[d];
  zs[d] = ln;
  __syncthreads();
  if (d < 128){
    float acc = b1[d];
    #pragma unroll 16
    for (int k=0;k<256;k++) acc = fmaf(zs[k], W1[k*128+d], acc);
    h1[d] = fmaxf(acc, 0.f);
  }
  __syncthreads();
  if (d < 2){
    float acc = b2[d];
    #pragma unroll 16
    for (int k=0;k<128;k++) acc = fmaf(h1[k], W2[k*2+d], acc);
    out[b*2+d] = acc;
  }
}

extern "C" void kernel_launch(void* const* d_in, const int* in_sizes, int n_in,
                              void* d_out, int out_size, void* d_ws, size_t ws_size,
                              hipStream_t stream){
  const float* x      = (const float*)d_in[0];
  const float* W_in   = (const float*)d_in[1];
  const float* b_in   = (const float*)d_in[2];
  const float* ln1_g  = (const float*)d_in[3];
  const float* ln1_b  = (const float*)d_in[4];
  const float* conv_w = (const float*)d_in[5];
  const float* conv_b = (const float*)d_in[6];
  const float* Wd     = (const float*)d_in[7];
  const float* bd     = (const float*)d_in[8];
  const float* WB     = (const float*)d_in[9];
  const float* bB     = (const float*)d_in[10];
  const float* WC     = (const float*)d_in[11];
  const float* bC     = (const float*)d_in[12];
  const float* A      = (const float*)d_in[13];
  const float* Wg     = (const float*)d_in[14];
  const float* bg     = (const float*)d_in[15];
  const float* filt_re= (const float*)d_in[16];
  const float* alpha  = (const float*)d_in[18];
  const float* beta   = (const float*)d_in[19];
  const float* lnc_g  = (const float*)d_in[20];
  const float* lnc_b  = (const float*)d_in[21];
  const float* W1     = (const float*)d_in[22];
  const float* b1     = (const float*)d_in[23];
  const float* W2     = (const float*)d_in[24];
  const float* b2     = (const float*)d_in[25];

  char* w = (char*)d_ws;
  float* xp   = (float*)(w);
  unsigned short* d16  = (unsigned short*)(w);
  unsigned short* bc16 = (unsigned short*)(w + 33554432);
  float2* xpz = (float2*)(w + 67108864);
  float* AB_A = (float*)(w + 67108864);
  float* AB_B = (float*)(w + 67108864 + 8388608);
  float* Hs   = (float*)(w + 67108864 + 16777216);
  float* part = (float*)(w + 67108864 + 25165824);
  unsigned short* xn16 = (unsigned short*)(w + 134217728);
  unsigned short* u16  = (unsigned short*)(w + 167772160);
  unsigned short* g16  = (unsigned short*)(w + 201326592);
  char* small = w + 234881024;
  // WdF frag-major fused Wd+Wbc (147456 B), then WgF frag-major (131072 B).
  unsigned short* WdF  = (unsigned short*)(small);
  unsigned short* WgF  = (unsigned short*)(small + 147456);
  float*  bbc = (float*)(small + 278528);
  float2* tw  = (float2*)(small + 278656);
  float*  T0  = (float*)(small + 295040);
  int*    rank= (int*)(small + 311424);
  (void)in_sizes; (void)n_in; (void)out_size; (void)ws_size;

  hipLaunchKernelGGL(k_prep, dim3(553), dim3(256), 0, stream,
                     Wd, Wg, WB, WC, bB, bC, WdF, WgF, bbc, tw);
  hipLaunchKernelGGL(k_xp, dim3(BS/16), dim3(256), 0, stream, x, W_in, b_in, xp);
  hipLaunchKernelGGL(k_lnconv, dim3(SS/16, BB), dim3(256), 0, stream,
                     xp, ln1_g, ln1_b, conv_w, conv_b, xn16, u16);
  hipLaunchKernelGGL(k_transpose, dim3(SS/32, DD/32, BB), dim3(32,8), 0, stream, xp, xpz);
  hipLaunchKernelGGL(k_fft, dim3(BB*128), dim3(256), 0, stream, xpz, tw, rank, T0);
  hipLaunchKernelGGL((k_gemm2<18,1>), dim3(BS/64), dim3(512), 0, stream,
                     u16, WdF, bd, bbc, d16, bc16);
  hipLaunchKernelGGL((k_gemm2<16,2>), dim3(BS/64), dim3(512), 0, stream,
                     xn16, WgF, bg, bbc, g16, bc16);
  hipLaunchKernelGGL(k_scanA, dim3(CH, DD/16, BB), dim3(256), 0, stream, d16, u16, bc16, A, AB_A, AB_B);
  hipLaunchKernelGGL(k_scanB, dim3(256), dim3(256), 0, stream, AB_A, AB_B, Hs);
  hipLaunchKernelGGL(k_scanC, dim3(CH, DD/16, BB), dim3(256), 0, stream, d16, u16, bc16, g16, A, Hs, part);
  hipLaunchKernelGGL(k_final, dim3(BB), dim3(256), 0, stream,
                     part, T0, rank, alpha, beta, filt_re, lnc_g, lnc_b, W1, b1, W2, b2, (float*)d_out);
}

// Round 6
// 300.948 us; speedup vs baseline: 1.3976x; 1.1460x over previous
//
#include <hip/hip_runtime.h>
#include <hip/hip_bf16.h>
#include <math.h>

#define BB 16
#define SS 4096
#define IN 64
#define DD 256
#define NN 16
#define KK 32
#define CH 32
#define LCH 128
#define BS (BB*SS)

typedef __attribute__((ext_vector_type(4))) float f32x4;
typedef __attribute__((ext_vector_type(8))) short bf16x8;

__device__ __forceinline__ float bf2f(unsigned short u){
  return __uint_as_float(((unsigned int)u)<<16);
}
__device__ __forceinline__ unsigned short f2bf(float f){
  unsigned int u = __float_as_uint(f);
  return (unsigned short)((u + 0x7fffu + ((u>>16)&1u)) >> 16);
}
// Fast activations: outputs are bf16 (8-bit mantissa) -> ~1e-5 rel err of
// v_exp/v_log/v_rcp is invisible. Saves ~40 VALU insts per call vs libm.
__device__ __forceinline__ float fast_softplus(float v){
  float e = __expf(-fabsf(v));
  return fmaxf(v, 0.f) + __logf(1.f + e);
}
__device__ __forceinline__ float fast_silu(float v){
  return v * __builtin_amdgcn_rcpf(1.f + __expf(-v));
}
// XOR-swizzled LDS addressing for 64x(256 bf16) tiles: row stride 512B,
// 16B slot index XORed with (row&7) -> conflict-free ds_read_b128 down columns.
__device__ __forceinline__ void* swz(void* base, int row, int byteoff){
  return (void*)((char*)base + (row<<9) + (byteoff ^ ((row&7)<<4)));
}
// FFT LDS swizzle on float2 index: involution, scrambles low4 with bits[7:4].
#define SW(i) ((i) ^ (((i)>>4)&15))

// ---------------- prep: fragment-major bf16 weights, bias concat, twiddles ----------------
// Frag-major layout: element for (jn, kc, lane, e) at ((jn*8+kc)*64+lane)*8+e,
// where lr=lane&15, lh=lane>>4, col n=jn*16+lr, row k=kc*32+lh*8+e.
// -> each MFMA B-fragment load is one lane-contiguous 1 KiB transaction.
__global__ void k_prep(const float* Wd, const float* Wg, const float* WB, const float* WC,
                       const float* bBv, const float* bCv,
                       unsigned short* WdF, unsigned short* WgF,
                       float* bbc, float2* tw){
  int id = blockIdx.x*256 + threadIdx.x;
  if (id < 73728){                     // fused Wd(jn 0..15) + WB/WC(jn 16,17)
    int jn = id >> 12; int rem = id & 4095;
    int kc = rem >> 9; int l8 = (rem >> 3) & 63; int e = id & 7;
    int lr = l8 & 15, lh = l8 >> 4;
    int k = kc*32 + lh*8 + e;
    float v;
    if (jn < 16){ int n = jn*16 + lr; v = Wd[k*256+n]; }
    else { int c = (jn-16)*16 + lr; v = (c<16) ? WB[k*16+c] : WC[k*16+(c-16)]; }
    WdF[id] = f2bf(v);
  }
  else if (id < 139264){               // Wg frag-major (jn 0..15)
    int o = id - 73728;
    int jn = o >> 12; int rem = o & 4095;
    int kc = rem >> 9; int l8 = (rem >> 3) & 63; int e = o & 7;
    int lr = l8 & 15, lh = l8 >> 4;
    int k = kc*32 + lh*8 + e;
    WgF[o] = f2bf(Wg[k*256 + jn*16 + lr]);
  }
  else if (id < 141312){ int k = id-139264;
    double a = -6.283185307179586476925287 * (double)k / 4096.0;
    tw[k] = make_float2((float)cos(a), (float)sin(a)); }
  else if (id < 141344){ int j = id-141312; bbc[j] = (j<16)? bBv[j] : bCv[j-16]; }
}

// ---------------- K1: xp = x @ W_in + b_in (f32) ----------------
__global__ __launch_bounds__(256) void k_xp(const float* x, const float* W_in, const float* b_in, float* xp){
  __shared__ float xl[16][68];
  int tid = threadIdx.x;
  int m0 = blockIdx.x*16;
  {
    int r = tid>>4, kq = tid&15;
    float4 v = *(const float4*)&x[(size_t)(m0+r)*IN + kq*4];
    *(float4*)&xl[r][kq*4] = v;
  }
  __syncthreads();
  int ty = tid>>6, tx = tid&63;
  int c0 = tx*4;
  float acc[4][4] = {};
  #pragma unroll 8
  for (int k=0;k<IN;k++){
    float4 wv = *(const float4*)&W_in[k*DD + c0];
    #pragma unroll
    for (int rr=0;rr<4;rr++){
      float xv = xl[ty*4+rr][k];
      acc[rr][0] = fmaf(xv, wv.x, acc[rr][0]);
      acc[rr][1] = fmaf(xv, wv.y, acc[rr][1]);
      acc[rr][2] = fmaf(xv, wv.z, acc[rr][2]);
      acc[rr][3] = fmaf(xv, wv.w, acc[rr][3]);
    }
  }
  float4 bv = *(const float4*)&b_in[c0];
  #pragma unroll
  for (int rr=0;rr<4;rr++){
    float4 o = make_float4(acc[rr][0]+bv.x, acc[rr][1]+bv.y, acc[rr][2]+bv.z, acc[rr][3]+bv.w);
    *(float4*)&xp[(size_t)(m0+ty*4+rr)*DD + c0] = o;
  }
}

// ---------------- K2: LayerNorm + depthwise conv(3) + silu ----------------
__global__ __launch_bounds__(256) void k_lnconv(const float* xp, const float* ln1_g, const float* ln1_b,
      const float* conv_w, const float* conv_b,
      unsigned short* xn16, unsigned short* u16){
  __shared__ float xs[18][260];
  __shared__ float lg[DD], lb[DD], c0w[DD], c1w[DD], c2w[DD], cbv[DD];
  int tid = threadIdx.x;
  int b = blockIdx.y; int t0 = blockIdx.x*16;
  lg[tid]=ln1_g[tid]; lb[tid]=ln1_b[tid];
  c0w[tid]=conv_w[tid*3]; c1w[tid]=conv_w[tid*3+1]; c2w[tid]=conv_w[tid*3+2];
  cbv[tid]=conv_b[tid];
  __syncthreads();
  int w = tid>>6, lane = tid&63;
  for (int r=w; r<18; r+=4){
    int t = t0 - 1 + r;
    bool valid = (t>=0) && (t<SS);
    float4 v = make_float4(0.f,0.f,0.f,0.f);
    if (valid) v = *(const float4*)&xp[((size_t)b*SS + t)*DD + lane*4];
    float s1 = v.x+v.y+v.z+v.w;
    float s2 = v.x*v.x+v.y*v.y+v.z*v.z+v.w*v.w;
    #pragma unroll
    for (int off=32; off; off>>=1){ s1 += __shfl_xor(s1,off); s2 += __shfl_xor(s2,off); }
    float mean = s1*(1.f/256.f);
    float var  = s2*(1.f/256.f) - mean*mean;
    float rstd = rsqrtf(var + 1e-5f);
    float vv[4] = {v.x,v.y,v.z,v.w};
    float o[4];
    #pragma unroll
    for (int i=0;i<4;i++){
      int d = lane*4+i;
      o[i] = valid ? ((vv[i]-mean)*rstd*lg[d] + lb[d]) : 0.f;
      xs[r][d] = o[i];
    }
    if (r>=1 && r<=16){
      ushort4 st;
      st.x=f2bf(o[0]); st.y=f2bf(o[1]); st.z=f2bf(o[2]); st.w=f2bf(o[3]);
      *(ushort4*)&xn16[((size_t)b*SS + t)*DD + lane*4] = st;
    }
  }
  __syncthreads();
  int d = tid;
  float w0=c0w[d], w1=c1w[d], w2=c2w[d], cb=cbv[d];
  #pragma unroll 4
  for (int rr=0; rr<16; rr++){
    float a0=xs[rr][d], a1=xs[rr+1][d], a2=xs[rr+2][d];
    float xc = a0*w0 + a1*w1 + a2*w2 + cb;
    u16[((size_t)b*SS + (t0+rr))*DD + d] = f2bf(fast_silu(xc));
  }
}

// ---------------- transpose xp -> paired-complex xpz [B][D/2][S] (float2 = d-pair) ----------------
__global__ void k_transpose(const float* xp, float2* xpz){
  __shared__ float tile[32][33];
  int b = blockIdx.z; int s0 = blockIdx.x*32; int d0 = blockIdx.y*32;
  int tx = threadIdx.x, ty = threadIdx.y;
  const float* src = xp + (size_t)b*SS*DD;
  #pragma unroll
  for (int i=0;i<4;i++) tile[ty+8*i][tx] = src[(size_t)(s0+ty+8*i)*DD + d0+tx];
  __syncthreads();
  float2* dst = xpz + (size_t)b*128*SS;
  #pragma unroll
  for (int i=0;i<2;i++){
    int pr = ty + 8*i;                 // local pair 0..15
    dst[(size_t)((d0>>1) + pr)*SS + s0 + tx] =
        make_float2(tile[tx][2*pr], tile[tx][2*pr+1]);
  }
}

// ---------------- fused single-pass GEMM: 64 rows x all-N, A in LDS, frag-major B from L2 ----------------
// NTOT = 16-col fragments total (18 = Wd(16)+WB/WC(2) fused; 16 = Wg).
// ACT applies to frags jn<16: 1=softplus, 2=silu. Frags jn>=16 (bc) get no act.
// B-loads software-pipelined: prefetch j+1's 8 coalesced 1KiB loads during j's MFMAs.
template<int NTOT, int ACT>
__global__ __launch_bounds__(512,2) void k_gemm2(const unsigned short* Ab, const unsigned short* Bt,
      const float* bias_main, const float* bias_bc,
      unsigned short* out_main, unsigned short* out_bc){
  __shared__ unsigned short As[64*256];   // 32 KiB
  const int NF = NTOT/2;
  int tid = threadIdx.x;
  int m0 = blockIdx.x*64;
  {
    const uint4* gA = (const uint4*)(Ab + (size_t)m0*256);
    #pragma unroll
    for (int i=0;i<4;i++){
      int f = tid + 512*i;               // f < 2048; row = f>>5 < 64
      uint4 v = gA[f];
      *(uint4*)swz(As, f>>5, (f&31)<<4) = v;
    }
  }
  __syncthreads();
  int wv = tid>>6, lane = tid&63;
  int wm = wv>>1, nh = wv&1;            // 4 m-waves x 2 n-halves
  int lr = lane&15, lh = lane>>4;
  const bf16x8* bbase = (const bf16x8*)(Bt + (size_t)(nh*NF)*4096 + (size_t)lane*8);
  // fragment (j,kc) at bbase[j*512 + kc*64]
  f32x4 acc[NF];
  #pragma unroll
  for (int j=0;j<NF;j++){ acc[j][0]=0.f; acc[j][1]=0.f; acc[j][2]=0.f; acc[j][3]=0.f; }
  bf16x8 bq[2][8];                      // ping-pong; all indices compile-time after unroll
  #pragma unroll
  for (int kc=0;kc<8;kc++) bq[0][kc] = bbase[kc*64];
  #pragma unroll
  for (int j=0;j<NF;j++){
    if (j+1 < NF){
      #pragma unroll
      for (int kc=0;kc<8;kc++) bq[(j+1)&1][kc] = bbase[(j+1)*512 + kc*64];
    }
    #pragma unroll
    for (int kc=0;kc<8;kc++){
      bf16x8 af = *(const bf16x8*)swz(As, wm*16+lr, kc*64+lh*16);
      acc[j] = __builtin_amdgcn_mfma_f32_16x16x32_bf16(af, bq[j&1][kc], acc[j], 0,0,0);
    }
  }
  #pragma unroll
  for (int j=0;j<NF;j++){
    int jn = nh*NF + j;
    if (jn < 16){
      int col = jn*16 + lr;
      float bs = bias_main[col];
      #pragma unroll
      for (int i=0;i<4;i++){
        int row = m0 + wm*16 + lh*4 + i;
        float v = acc[j][i] + bs;
        if (ACT==1) v = fast_softplus(v);
        if (ACT==2) v = fast_silu(v);
        out_main[(size_t)row*256 + col] = f2bf(v);
      }
    } else {
      int col = (jn-16)*16 + lr;
      float bs = bias_bc[col];
      #pragma unroll
      for (int i=0;i<4;i++){
        int row = m0 + wm*16 + lh*4 + i;
        out_bc[(size_t)row*32 + col] = f2bf(acc[j][i] + bs);
      }
    }
  }
}

// ---------------- FFT: two-for-one 4096-pt radix-4 Stockham; DC rank + T0 for 2 channels ----------------
__global__ __launch_bounds__(256,2) void k_fft(const float2* xpz, const float2* twg, int* rank, float* T0){
  __shared__ float2 bufA[4096];
  __shared__ float2 bufB[4096];
  int blk = blockIdx.x;              // 0..2047
  int b = blk >> 7, pair = blk & 127;
  int tid = threadIdx.x;
  const float4* src4 = (const float4*)(xpz + ((size_t)b*128 + pair)*SS);
  #pragma unroll
  for (int q=tid; q<2048; q+=256){
    float4 v = src4[q];
    bufA[SW(2*q)]   = make_float2(v.x, v.y);
    bufA[SW(2*q+1)] = make_float2(v.z, v.w);
  }
  __syncthreads();
  float2* s = bufA; float2* d = bufB;
  for (int st=0; st<6; st++){
    int m = 1<<(2*st);
    #pragma unroll
    for (int it=0; it<4; it++){
      int i = tid + 256*it;          // i in [0,1024)
      int k4 = i & (m-1);
      int tb = i - k4;               // j4*m < 1024
      float2 a0 = s[SW(i)];
      float2 a1 = s[SW(i+1024)];
      float2 a2 = s[SW(i+2048)];
      float2 a3 = s[SW(i+3072)];
      float2 w1 = twg[tb];
      float2 w2 = make_float2(fmaf(w1.x,w1.x,-w1.y*w1.y), 2.f*w1.x*w1.y);
      float2 w3 = make_float2(fmaf(w1.x,w2.x,-w1.y*w2.y), fmaf(w1.x,w2.y, w1.y*w2.x));
      float s0x=a0.x+a2.x, s0y=a0.y+a2.y;
      float s1x=a0.x-a2.x, s1y=a0.y-a2.y;
      float s2x=a1.x+a3.x, s2y=a1.y+a3.y;
      float t3x=a1.y-a3.y, t3y=a3.x-a1.x;     // -i*(a1-a3)
      int base = 4*i - 3*k4;
      d[SW(base)] = make_float2(s0x+s2x, s0y+s2y);
      float b1x = s1x+t3x, b1y = s1y+t3y;
      d[SW(base+m)]   = make_float2(fmaf(w1.x,b1x,-w1.y*b1y), fmaf(w1.x,b1y, w1.y*b1x));
      float b2x = s0x-s2x, b2y = s0y-s2y;
      d[SW(base+2*m)] = make_float2(fmaf(w2.x,b2x,-w2.y*b2y), fmaf(w2.x,b2y, w2.y*b2x));
      float b3x = s1x-t3x, b3y = s1y-t3y;
      d[SW(base+3*m)] = make_float2(fmaf(w3.x,b3x,-w3.y*b3y), fmaf(w3.x,b3y, w3.y*b3x));
    }
    __syncthreads();
    float2* t = s; s = d; d = t;
  }
  // 6 swaps -> result (natural order) back in bufA == s; bufB dead
  float2 z0 = s[0];
  float thx = 4.f*z0.x*z0.x, thy = 4.f*z0.y*z0.y;
  int cx=0, cy=0;
  #pragma unroll
  for (int j=0;j<8;j++){
    int f = 1 + tid + 256*j;         // bins 1..2048
    float2 zf = s[SW(f)];
    float2 zc = s[SW(4096-f)];
    float sxr = zf.x+zc.x, sxi = zf.y-zc.y;   // Zf + conj(Z_{N-f})
    float syr = zf.x-zc.x, syi = zf.y+zc.y;   // Zf - conj(Z_{N-f})
    cx += (fmaf(sxr,sxr,sxi*sxi) > thx) ? 1 : 0;
    cy += (fmaf(syr,syr,syi*syi) > thy) ? 1 : 0;
  }
  #pragma unroll
  for (int off=32; off; off>>=1){ cx += __shfl_xor(cx, off); cy += __shfl_xor(cy, off); }
  int* scr = (int*)bufB;
  if ((tid&63)==0){ scr[tid>>6] = cx; scr[4+(tid>>6)] = cy; }
  __syncthreads();
  if (tid==0){
    int r0 = b*256 + 2*pair;
    rank[r0]   = scr[0]+scr[1]+scr[2]+scr[3];
    rank[r0+1] = scr[4]+scr[5]+scr[6]+scr[7];
    T0[r0]   = z0.x;
    T0[r0+1] = z0.y;
  }
}

// ---------------- scan pass A: per-chunk (A,B) composition ----------------
__global__ __launch_bounds__(256) void k_scanA(const unsigned short* d16, const unsigned short* u16,
      const unsigned short* bc16, const float* Aw, float* AB_A, float* AB_B){
  __shared__ float duo[16][2*LCH+4];   // [dcol][{de,du} x t]
  __shared__ float bmL[16][LCH+4];     // [n][t]
  int c = blockIdx.x, dg = blockIdx.y, b = blockIdx.z;
  int t0 = c*LCH, d0 = dg*16;
  int tid = threadIdx.x;
  {
    int tt = tid>>1, half = tid&1;
    size_t base = ((size_t)b*SS + (t0+tt))*DD + d0 + half*8;
    uint4 dv = *(const uint4*)(d16 + base);
    uint4 uv = *(const uint4*)(u16 + base);
    const unsigned short* dp=(const unsigned short*)&dv;
    const unsigned short* up=(const unsigned short*)&uv;
    #pragma unroll
    for (int i=0;i<8;i++){
      float d_ = bf2f(dp[i]);
      duo[half*8+i][2*tt]   = d_;
      duo[half*8+i][2*tt+1] = d_*bf2f(up[i]);
    }
    size_t bbi = ((size_t)b*SS + (t0+tt))*32 + half*8;
    uint4 bv = *(const uint4*)(bc16 + bbi);
    const unsigned short* bp=(const unsigned short*)&bv;
    #pragma unroll
    for (int i=0;i<8;i++) bmL[half*8+i][tt] = bf2f(bp[i]);
  }
  __syncthreads();
  int n = tid&15, dl = tid>>4;
  float aw = Aw[(d0+dl)*16 + n];
  float Ac = 1.f, Bc = 0.f;
  #pragma unroll
  for (int tt=0; tt<LCH; tt+=4){
    float4 bm4 = *(const float4*)&bmL[n][tt];
    float4 q0  = *(const float4*)&duo[dl][2*tt];
    float4 q1  = *(const float4*)&duo[dl][2*tt+4];
    float a;
    a = fmaf(q0.x, aw, 1.f); Ac *= a; Bc = fmaf(a, Bc, q0.y*bm4.x);
    a = fmaf(q0.z, aw, 1.f); Ac *= a; Bc = fmaf(a, Bc, q0.w*bm4.y);
    a = fmaf(q1.x, aw, 1.f); Ac *= a; Bc = fmaf(a, Bc, q1.y*bm4.z);
    a = fmaf(q1.z, aw, 1.f); Ac *= a; Bc = fmaf(a, Bc, q1.w*bm4.w);
  }
  int idx = c*65536 + b*4096 + (d0+dl)*16 + n;
  AB_A[idx] = Ac;
  AB_B[idx] = Bc;
}

// ---------------- scan pass B: prefix over chunks ----------------
__global__ void k_scanB(const float* AB_A, const float* AB_B, float* Hs){
  int tid = blockIdx.x*256 + threadIdx.x;
  float h = 0.f;
  #pragma unroll
  for (int c=0;c<CH;c++){
    Hs[c*65536 + tid] = h;
    h = fmaf(AB_A[c*65536 + tid], h, AB_B[c*65536 + tid]);
  }
}

// ---------------- scan pass C: re-scan, accumulate sum_t (y*g) per (b,d,chunk) ----------------
__global__ __launch_bounds__(256) void k_scanC(const unsigned short* d16, const unsigned short* u16,
      const unsigned short* bc16, const unsigned short* g16, const float* Aw, const float* Hs, float* part){
  __shared__ float duo[16][2*LCH+4];   // [dcol][{de,du} x t]
  __shared__ float ggL[16][LCH+4];     // [dcol][t]
  __shared__ float bcp[16][2*LCH+4];   // [n][{bm,cm} x t]
  int c = blockIdx.x, dg = blockIdx.y, b = blockIdx.z;
  int t0 = c*LCH, d0 = dg*16;
  int tid = threadIdx.x;
  {
    int tt = tid>>1, half = tid&1;
    size_t base = ((size_t)b*SS + (t0+tt))*DD + d0 + half*8;
    uint4 dv = *(const uint4*)(d16 + base);
    uint4 uv = *(const uint4*)(u16 + base);
    uint4 gv = *(const uint4*)(g16 + base);
    size_t bbi = ((size_t)b*SS + (t0+tt))*32 + half*8;
    uint4 bv = *(const uint4*)(bc16 + bbi);
    uint4 cv = *(const uint4*)(bc16 + bbi + 16);
    const unsigned short* dp=(const unsigned short*)&dv;
    const unsigned short* up=(const unsigned short*)&uv;
    const unsigned short* gp=(const unsigned short*)&gv;
    const unsigned short* bp=(const unsigned short*)&bv;
    const unsigned short* cp=(const unsigned short*)&cv;
    #pragma unroll
    for (int i=0;i<8;i++){
      float d_ = bf2f(dp[i]);
      duo[half*8+i][2*tt]   = d_;
      duo[half*8+i][2*tt+1] = d_*bf2f(up[i]);
      ggL[half*8+i][tt]     = bf2f(gp[i]);
      bcp[half*8+i][2*tt]   = bf2f(bp[i]);
      bcp[half*8+i][2*tt+1] = bf2f(cp[i]);
    }
  }
  __syncthreads();
  int n = tid&15, dl = tid>>4;
  float aw = Aw[(d0+dl)*16 + n];
  float h = Hs[c*65536 + b*4096 + (d0+dl)*16 + n];
  float acc = 0.f;
  #pragma unroll
  for (int tt=0; tt<LCH; tt+=4){
    float4 gg4 = *(const float4*)&ggL[dl][tt];
    float4 q0  = *(const float4*)&duo[dl][2*tt];
    float4 q1  = *(const float4*)&duo[dl][2*tt+4];
    float4 p0  = *(const float4*)&bcp[n][2*tt];
    float4 p1  = *(const float4*)&bcp[n][2*tt+4];
    float a;
    a = fmaf(q0.x, aw, 1.f); h = fmaf(a, h, q0.y*p0.x); acc = fmaf(p0.y*gg4.x, h, acc);
    a = fmaf(q0.z, aw, 1.f); h = fmaf(a, h, q0.w*p0.z); acc = fmaf(p0.w*gg4.y, h, acc);
    a = fmaf(q1.x, aw, 1.f); h = fmaf(a, h, q1.y*p1.x); acc = fmaf(p1.y*gg4.z, h, acc);
    a = fmaf(q1.z, aw, 1.f); h = fmaf(a, h, q1.w*p1.z); acc = fmaf(p1.w*gg4.w, h, acc);
  }
  #pragma unroll
  for (int off=8; off; off>>=1) acc += __shfl_xor(acc, off, 16);
  if (n==0) part[(size_t)(b*256 + d0+dl)*CH + c] = acc;
}

// ---------------- final: zp assembly + LN + 2-layer MLP ----------------
__global__ __launch_bounds__(256) void k_final(const float* part, const float* T0, const int* rank,
      const float* alpha, const float* beta, const float* filt_re,
      const float* lnc_g, const float* lnc_b,
      const float* W1, const float* b1, const float* W2, const float* b2,
      float* out){
  __shared__ float zs[256];
  __shared__ float h1[128];
  __shared__ float red[8];
  int b = blockIdx.x, d = threadIdx.x;
  int row = b*256 + d;
  float ps = 0.f;
  #pragma unroll
  for (int c=0;c<CH;c++) ps += part[(size_t)row*CH + c];
  float ssm_mean = ps * (1.f/4096.f);
  float t0v = T0[row];
  float mxp = t0v * (1.f/4096.f);
  int r = rank[row];
  float spec = (r < KK) ? t0v * filt_re[r*DD + d] * (1.f/4096.f) : 0.f;
  float zp = alpha[d]*(mxp + ssm_mean) + beta[d]*spec;
  float s1 = zp, s2 = zp*zp;
  #pragma unroll
  for (int off=32; off; off>>=1){ s1 += __shfl_xor(s1,off); s2 += __shfl_xor(s2,off); }
  if ((d&63)==0){ red[d>>6] = s1; red[4+(d>>6)] = s2; }
  __syncthreads();
  float mean = (red[0]+red[1]+red[2]+red[3]) * (1.f/256.f);
  float var  = (red[4]+red[5]+red[6]+red[7]) * (1.f/256.f) - mean*mean;
  float ln = (zp-mean)*rsqrtf(var+1e-5f)*lnc_g[d] + lnc_b[d];
  zs[d] = ln;
  __syncthreads();
  if (d < 128){
    float acc = b1[d];
    #pragma unroll 16
    for (int k=0;k<256;k++) acc = fmaf(zs[k], W1[k*128+d], acc);
    h1[d] = fmaxf(acc, 0.f);
  }
  __syncthreads();
  if (d < 2){
    float acc = b2[d];
    #pragma unroll 16
    for (int k=0;k<128;k++) acc = fmaf(h1[k], W2[k*2+d], acc);
    out[b*2+d] = acc;
  }
}

extern "C" void kernel_launch(void* const* d_in, const int* in_sizes, int n_in,
                              void* d_out, int out_size, void* d_ws, size_t ws_size,
                              hipStream_t stream){
  const float* x      = (const float*)d_in[0];
  const float* W_in   = (const float*)d_in[1];
  const float* b_in   = (const float*)d_in[2];
  const float* ln1_g  = (const float*)d_in[3];
  const float* ln1_b  = (const float*)d_in[4];
  const float* conv_w = (const float*)d_in[5];
  const float* conv_b = (const float*)d_in[6];
  const float* Wd     = (const float*)d_in[7];
  const float* bd     = (const float*)d_in[8];
  const float* WB     = (const float*)d_in[9];
  const float* bB     = (const float*)d_in[10];
  const float* WC     = (const float*)d_in[11];
  const float* bC     = (const float*)d_in[12];
  const float* A      = (const float*)d_in[13];
  const float* Wg     = (const float*)d_in[14];
  const float* bg     = (const float*)d_in[15];
  const float* filt_re= (const float*)d_in[16];
  const float* alpha  = (const float*)d_in[18];
  const float* beta   = (const float*)d_in[19];
  const float* lnc_g  = (const float*)d_in[20];
  const float* lnc_b  = (const float*)d_in[21];
  const float* W1     = (const float*)d_in[22];
  const float* b1     = (const float*)d_in[23];
  const float* W2     = (const float*)d_in[24];
  const float* b2     = (const float*)d_in[25];

  char* w = (char*)d_ws;
  float* xp   = (float*)(w);
  unsigned short* d16  = (unsigned short*)(w);
  unsigned short* bc16 = (unsigned short*)(w + 33554432);
  float2* xpz = (float2*)(w + 67108864);
  float* AB_A = (float*)(w + 67108864);
  float* AB_B = (float*)(w + 67108864 + 8388608);
  float* Hs   = (float*)(w + 67108864 + 16777216);
  float* part = (float*)(w + 67108864 + 25165824);
  unsigned short* xn16 = (unsigned short*)(w + 134217728);
  unsigned short* u16  = (unsigned short*)(w + 167772160);
  unsigned short* g16  = (unsigned short*)(w + 201326592);
  char* small = w + 234881024;
  // WdF frag-major fused Wd+Wbc (147456 B), then WgF frag-major (131072 B).
  unsigned short* WdF  = (unsigned short*)(small);
  unsigned short* WgF  = (unsigned short*)(small + 147456);
  float*  bbc = (float*)(small + 278528);
  float2* tw  = (float2*)(small + 278656);
  float*  T0  = (float*)(small + 295040);
  int*    rank= (int*)(small + 311424);
  (void)in_sizes; (void)n_in; (void)out_size; (void)ws_size;

  hipLaunchKernelGGL(k_prep, dim3(553), dim3(256), 0, stream,
                     Wd, Wg, WB, WC, bB, bC, WdF, WgF, bbc, tw);
  hipLaunchKernelGGL(k_xp, dim3(BS/16), dim3(256), 0, stream, x, W_in, b_in, xp);
  hipLaunchKernelGGL(k_lnconv, dim3(SS/16, BB), dim3(256), 0, stream,
                     xp, ln1_g, ln1_b, conv_w, conv_b, xn16, u16);
  hipLaunchKernelGGL(k_transpose, dim3(SS/32, DD/32, BB), dim3(32,8), 0, stream, xp, xpz);
  hipLaunchKernelGGL(k_fft, dim3(BB*128), dim3(256), 0, stream, xpz, tw, rank, T0);
  hipLaunchKernelGGL((k_gemm2<18,1>), dim3(BS/64), dim3(512), 0, stream,
                     u16, WdF, bd, bbc, d16, bc16);
  hipLaunchKernelGGL((k_gemm2<16,2>), dim3(BS/64), dim3(512), 0, stream,
                     xn16, WgF, bg, bbc, g16, bc16);
  hipLaunchKernelGGL(k_scanA, dim3(CH, DD/16, BB), dim3(256), 0, stream, d16, u16, bc16, A, AB_A, AB_B);
  hipLaunchKernelGGL(k_scanB, dim3(256), dim3(256), 0, stream, AB_A, AB_B, Hs);
  hipLaunchKernelGGL(k_scanC, dim3(CH, DD/16, BB), dim3(256), 0, stream, d16, u16, bc16, g16, A, Hs, part);
  hipLaunchKernelGGL(k_final, dim3(BB), dim3(256), 0, stream,
                     part, T0, rank, alpha, beta, filt_re, lnc_g, lnc_b, W1, b1, W2, b2, (float*)d_out);
}